// Round 3
// baseline (148.540 us; speedup 1.0000x reference)
//
#include <hip/hip_runtime.h>

#define N_ROWS 4096
#define TN 8192      // 2N
#define DIM 128
// z is pre-scaled by sqrt(10*log2(e)) so MFMA yields 10*log2e*sim directly:
// exp(10*s) = exp2( (sqrt(c)*zi) . (sqrt(c)*zj) ),  c = 10*log2(e)
#define SQRT_C 3.79828266f

// ws layout: [0,8192) f32 denom | [8192,9216) f32 pos_part | z bf16 at byte 36864
#define Z_BYTE_OFF 36864

typedef __attribute__((ext_vector_type(8))) short short8;
typedef __attribute__((ext_vector_type(4))) float f32x4;

static __device__ __forceinline__ ushort f2bf(float f) {
    union { float f; unsigned u; } a; a.f = f;
    unsigned r = a.u + 0x7FFF + ((a.u >> 16) & 1);  // round-to-nearest-even
    return (ushort)(r >> 16);
}

// --- Kernel A: normalize rows -> scaled bf16 z[8192][128]; per-block positives partial ---
__global__ __launch_bounds__(256) void prep_kernel(
    const float* __restrict__ anchor, const float* __restrict__ target,
    ushort* __restrict__ z, float* __restrict__ pos_part)
{
    int wave = threadIdx.x >> 6;
    int lane = threadIdx.x & 63;
    int i    = blockIdx.x * 4 + wave;
    float2 a = ((const float2*)(anchor + (size_t)i * DIM))[lane];
    float2 t = ((const float2*)(target + (size_t)i * DIM))[lane];
    float sa = a.x * a.x + a.y * a.y;
    float st = t.x * t.x + t.y * t.y;
    float dt = a.x * t.x + a.y * t.y;
    #pragma unroll
    for (int m = 1; m < 64; m <<= 1) {
        sa += __shfl_xor(sa, m, 64);
        st += __shfl_xor(st, m, 64);
        dt += __shfl_xor(dt, m, 64);
    }
    float rsa = rsqrtf(fmaxf(sa, 1e-12f)) ;
    float rst = rsqrtf(fmaxf(st, 1e-12f));
    float ka = rsa * SQRT_C, kt = rst * SQRT_C;
    ushort2 za, zt;
    za.x = f2bf(a.x * ka); za.y = f2bf(a.y * ka);
    zt.x = f2bf(t.x * kt); zt.y = f2bf(t.y * kt);
    ((ushort2*)(z + (size_t)i * DIM))[lane] = za;
    ((ushort2*)(z + (size_t)(i + N_ROWS) * DIM))[lane] = zt;
    __shared__ float red[4];
    if (lane == 0) red[wave] = dt * rsa * rst;
    __syncthreads();
    if (threadIdx.x == 0)
        pos_part[blockIdx.x] = red[0] + red[1] + red[2] + red[3];
}

// --- Kernel B: denom_i += sum_{j in chunk, j!=i} exp2(z_i . z_j)  (z pre-scaled) ---
// Block: 128 rows x 512 cols, 4 waves as 2x2 -> wave owns 64 rows x 256 cols.
// A resident in regs; B streamed from L2 with register ping-pong.
__global__ __launch_bounds__(256, 4) void simgemm_kernel(
    const ushort* __restrict__ z, float* __restrict__ denom)
{
    int wave = threadIdx.x >> 6;
    int lane = threadIdx.x & 63;
    int r = lane & 15;       // A/B row-within-tile; C col
    int g = lane >> 4;       // k-group; C row group
    int wr = wave >> 1, wc = wave & 1;
    int rowbase = blockIdx.x * 128 + wr * 64;
    int wcol    = blockIdx.y * 512 + wc * 256;

    // A fragments: 64 rows x 128 k resident
    short8 a[4][4];
    #pragma unroll
    for (int rt = 0; rt < 4; ++rt)
        #pragma unroll
        for (int kt = 0; kt < 4; ++kt)
            a[rt][kt] = *(const short8*)(z + (size_t)(rowbase + rt * 16 + r) * DIM
                                           + kt * 32 + g * 8);

    float ps[4][4];
    #pragma unroll
    for (int rt = 0; rt < 4; ++rt)
        #pragma unroll
        for (int q = 0; q < 4; ++q) ps[rt][q] = 0.0f;

    // wave-uniform: do diagonal elements fall in this wave's tile?
    bool wavediag = ((unsigned)(rowbase - wcol) < 256u);

    const ushort* pb = z + (size_t)(wcol + r) * DIM + g * 8;

#define LOADB(buf, ptr)                                \
    {   buf[0] = *(const short8*)(ptr);                \
        buf[1] = *(const short8*)((ptr) + 32);         \
        buf[2] = *(const short8*)((ptr) + 64);         \
        buf[3] = *(const short8*)((ptr) + 96); }

#define COMPUTE(ct, b)                                                        \
    {   int c0 = wcol + (ct) * 16;                                            \
        bool dtile = wavediag && ((unsigned)(c0 - rowbase) < 64u);            \
        if (!dtile) {                                                         \
            _Pragma("unroll")                                                 \
            for (int rt = 0; rt < 4; ++rt) {                                  \
                f32x4 acc = {0.f, 0.f, 0.f, 0.f};                             \
                _Pragma("unroll")                                             \
                for (int kt = 0; kt < 4; ++kt)                                \
                    acc = __builtin_amdgcn_mfma_f32_16x16x32_bf16(            \
                        a[rt][kt], b[kt], acc, 0, 0, 0);                      \
                _Pragma("unroll")                                             \
                for (int q = 0; q < 4; ++q)                                   \
                    ps[rt][q] += __builtin_amdgcn_exp2f(acc[q]);              \
            }                                                                 \
        } else {                                                              \
            int gcol = c0 + r;                                                \
            _Pragma("unroll")                                                 \
            for (int rt = 0; rt < 4; ++rt) {                                  \
                f32x4 acc = {0.f, 0.f, 0.f, 0.f};                             \
                _Pragma("unroll")                                             \
                for (int kt = 0; kt < 4; ++kt)                                \
                    acc = __builtin_amdgcn_mfma_f32_16x16x32_bf16(            \
                        a[rt][kt], b[kt], acc, 0, 0, 0);                      \
                _Pragma("unroll")                                             \
                for (int q = 0; q < 4; ++q) {                                 \
                    float e = __builtin_amdgcn_exp2f(acc[q]);                 \
                    int grow = rowbase + rt * 16 + g * 4 + q;                 \
                    ps[rt][q] += (grow == gcol) ? 0.0f : e;                   \
                }                                                             \
            }                                                                 \
        } }

    short8 b0[4], b1[4];
    LOADB(b0, pb);
    for (int ct = 0; ct < 16; ct += 2) {
        const ushort* pn = pb + (ct + 1) * (16 * DIM);
        LOADB(b1, pn);                       // prefetch odd tile
        COMPUTE(ct, b0);                     // compute even tile
        if (ct + 2 < 16) {
            const ushort* pn2 = pb + (ct + 2) * (16 * DIM);
            LOADB(b0, pn2);                  // prefetch next even tile
        }
        COMPUTE(ct + 1, b1);                 // compute odd tile
    }
#undef LOADB
#undef COMPUTE

    // reduce across the 16 lanes sharing g, then one atomic per row
    #pragma unroll
    for (int rt = 0; rt < 4; ++rt)
        #pragma unroll
        for (int q = 0; q < 4; ++q) {
            float v = ps[rt][q];
            v += __shfl_xor(v, 1, 64);
            v += __shfl_xor(v, 2, 64);
            v += __shfl_xor(v, 4, 64);
            v += __shfl_xor(v, 8, 64);
            if (r == 0)
                atomicAdd(&denom[rowbase + rt * 16 + g * 4 + q], v);
        }
}

// --- Kernel C: loss = (sum_i log denom_i - 20 * sum pos) / 2N ---
__global__ __launch_bounds__(1024) void finalize_kernel(
    const float* __restrict__ denom, const float* __restrict__ pos_part,
    float* __restrict__ out)
{
    int tid = threadIdx.x;
    float slog = 0.0f;
    #pragma unroll
    for (int u = 0; u < TN / 1024; ++u) slog += logf(denom[u * 1024 + tid]);
    float spos = pos_part[tid];
    #pragma unroll
    for (int m = 1; m < 64; m <<= 1) {
        slog += __shfl_xor(slog, m, 64);
        spos += __shfl_xor(spos, m, 64);
    }
    __shared__ float redl[16], redp[16];
    if ((tid & 63) == 0) { redl[tid >> 6] = slog; redp[tid >> 6] = spos; }
    __syncthreads();
    if (tid == 0) {
        float tl = 0.0f, tp = 0.0f;
        #pragma unroll
        for (int i = 0; i < 16; ++i) { tl += redl[i]; tp += redp[i]; }
        out[0] = (tl - 20.0f * tp) / (float)TN;
    }
}

extern "C" void kernel_launch(void* const* d_in, const int* in_sizes, int n_in,
                              void* d_out, int out_size, void* d_ws, size_t ws_size,
                              hipStream_t stream) {
    const float* anchor = (const float*)d_in[0];
    const float* target = (const float*)d_in[1];
    float* denom    = (float*)d_ws;
    float* pos_part = denom + TN;          // 1024 entries
    ushort* z       = (ushort*)((char*)d_ws + Z_BYTE_OFF);

    hipMemsetAsync(d_ws, 0, TN * sizeof(float), stream);
    prep_kernel<<<N_ROWS / 4, 256, 0, stream>>>(anchor, target, z, pos_part);
    simgemm_kernel<<<dim3(TN / 128, 16), 256, 0, stream>>>(z, denom);
    finalize_kernel<<<1, 1024, 0, stream>>>(denom, pos_part, (float*)d_out);
}

// Round 4
// 104.029 us; speedup vs baseline: 1.4279x; 1.4279x over previous
//
#include <hip/hip_runtime.h>

#define N_ROWS 4096
#define TN 8192      // 2N
#define DIM 128
// z is pre-scaled by sqrt(10*log2(e)) so MFMA yields 10*log2e*sim directly:
// exp(10*s) = exp2( (sqrt(c)*zi) . (sqrt(c)*zj) ),  c = 10*log2(e)
#define SQRT_C 3.79828266f

// ws layout: [0,8192) f32 denom | [8192,9216) f32 pos_part | z bf16 at byte 36864
#define Z_BYTE_OFF 36864

typedef __attribute__((ext_vector_type(8))) short short8;
typedef __attribute__((ext_vector_type(4))) float f32x4;

static __device__ __forceinline__ ushort f2bf(float f) {
    union { float f; unsigned u; } a; a.f = f;
    unsigned r = a.u + 0x7FFF + ((a.u >> 16) & 1);  // round-to-nearest-even
    return (ushort)(r >> 16);
}

// --- Kernel A: normalize rows -> scaled bf16 z[8192][128]; per-block positives partial ---
__global__ __launch_bounds__(256) void prep_kernel(
    const float* __restrict__ anchor, const float* __restrict__ target,
    ushort* __restrict__ z, float* __restrict__ pos_part)
{
    int wave = threadIdx.x >> 6;
    int lane = threadIdx.x & 63;
    int i    = blockIdx.x * 4 + wave;
    float2 a = ((const float2*)(anchor + (size_t)i * DIM))[lane];
    float2 t = ((const float2*)(target + (size_t)i * DIM))[lane];
    float sa = a.x * a.x + a.y * a.y;
    float st = t.x * t.x + t.y * t.y;
    float dt = a.x * t.x + a.y * t.y;
    #pragma unroll
    for (int m = 1; m < 64; m <<= 1) {
        sa += __shfl_xor(sa, m, 64);
        st += __shfl_xor(st, m, 64);
        dt += __shfl_xor(dt, m, 64);
    }
    float rsa = rsqrtf(fmaxf(sa, 1e-12f));
    float rst = rsqrtf(fmaxf(st, 1e-12f));
    float ka = rsa * SQRT_C, kt = rst * SQRT_C;
    ushort2 za, zt;
    za.x = f2bf(a.x * ka); za.y = f2bf(a.y * ka);
    zt.x = f2bf(t.x * kt); zt.y = f2bf(t.y * kt);
    ((ushort2*)(z + (size_t)i * DIM))[lane] = za;
    ((ushort2*)(z + (size_t)(i + N_ROWS) * DIM))[lane] = zt;
    __shared__ float red[4];
    if (lane == 0) red[wave] = dt * rsa * rst;
    __syncthreads();
    if (threadIdx.x == 0)
        pos_part[blockIdx.x] = red[0] + red[1] + red[2] + red[3];
}

// --- Kernel B: denom_i += sum_{j in chunk, j!=i} exp2(z_i . z_j)  (z pre-scaled) ---
// Block: 128 rows x 512 cols, 4 waves as 2x2 -> wave owns 64 rows x 256 cols.
// A resident in regs; B streamed from L2 with register ping-pong.
// NOTE: no min-waves launch_bounds — (256,4) forced VGPR=64 and spilled 30 MB
// to scratch (R3: WRITE_SIZE 2->29.7 MB, dur 45->93 us). Default bound gave
// spill-free 84 VGPR in R2.
__global__ __launch_bounds__(256) void simgemm_kernel(
    const ushort* __restrict__ z, float* __restrict__ denom)
{
    int wave = threadIdx.x >> 6;
    int lane = threadIdx.x & 63;
    int r = lane & 15;       // A/B row-within-tile; C col
    int g = lane >> 4;       // k-group; C row group
    int wr = wave >> 1, wc = wave & 1;
    int rowbase = blockIdx.x * 128 + wr * 64;
    int wcol    = blockIdx.y * 512 + wc * 256;

    // A fragments: 64 rows x 128 k resident
    short8 a[4][4];
    #pragma unroll
    for (int rt = 0; rt < 4; ++rt)
        #pragma unroll
        for (int kt = 0; kt < 4; ++kt)
            a[rt][kt] = *(const short8*)(z + (size_t)(rowbase + rt * 16 + r) * DIM
                                           + kt * 32 + g * 8);

    float ps[4][4];
    #pragma unroll
    for (int rt = 0; rt < 4; ++rt)
        #pragma unroll
        for (int q = 0; q < 4; ++q) ps[rt][q] = 0.0f;

    // wave-uniform: do diagonal elements fall in this wave's tile?
    bool wavediag = ((unsigned)(rowbase - wcol) < 256u);

    const ushort* pb = z + (size_t)(wcol + r) * DIM + g * 8;

#define LOADB(buf, ptr)                                \
    {   buf[0] = *(const short8*)(ptr);                \
        buf[1] = *(const short8*)((ptr) + 32);         \
        buf[2] = *(const short8*)((ptr) + 64);         \
        buf[3] = *(const short8*)((ptr) + 96); }

#define COMPUTE(ct, b)                                                        \
    {   int c0 = wcol + (ct) * 16;                                            \
        bool dtile = wavediag && ((unsigned)(c0 - rowbase) < 64u);            \
        if (!dtile) {                                                         \
            _Pragma("unroll")                                                 \
            for (int rt = 0; rt < 4; ++rt) {                                  \
                f32x4 acc = {0.f, 0.f, 0.f, 0.f};                             \
                _Pragma("unroll")                                             \
                for (int kt = 0; kt < 4; ++kt)                                \
                    acc = __builtin_amdgcn_mfma_f32_16x16x32_bf16(            \
                        a[rt][kt], b[kt], acc, 0, 0, 0);                      \
                _Pragma("unroll")                                             \
                for (int q = 0; q < 4; ++q)                                   \
                    ps[rt][q] += __builtin_amdgcn_exp2f(acc[q]);              \
            }                                                                 \
        } else {                                                              \
            int gcol = c0 + r;                                                \
            _Pragma("unroll")                                                 \
            for (int rt = 0; rt < 4; ++rt) {                                  \
                f32x4 acc = {0.f, 0.f, 0.f, 0.f};                             \
                _Pragma("unroll")                                             \
                for (int kt = 0; kt < 4; ++kt)                                \
                    acc = __builtin_amdgcn_mfma_f32_16x16x32_bf16(            \
                        a[rt][kt], b[kt], acc, 0, 0, 0);                      \
                _Pragma("unroll")                                             \
                for (int q = 0; q < 4; ++q) {                                 \
                    float e = __builtin_amdgcn_exp2f(acc[q]);                 \
                    int grow = rowbase + rt * 16 + g * 4 + q;                 \
                    ps[rt][q] += (grow == gcol) ? 0.0f : e;                   \
                }                                                             \
            }                                                                 \
        } }

    short8 b0[4], b1[4];
    LOADB(b0, pb);
    for (int ct = 0; ct < 16; ct += 2) {
        const ushort* pn = pb + (ct + 1) * (16 * DIM);
        LOADB(b1, pn);                       // prefetch odd tile
        COMPUTE(ct, b0);                     // compute even tile
        if (ct + 2 < 16) {
            const ushort* pn2 = pb + (ct + 2) * (16 * DIM);
            LOADB(b0, pn2);                  // prefetch next even tile
        }
        COMPUTE(ct + 1, b1);                 // compute odd tile
    }
#undef LOADB
#undef COMPUTE

    // reduce across the 16 lanes sharing g, then one atomic per row
    #pragma unroll
    for (int rt = 0; rt < 4; ++rt)
        #pragma unroll
        for (int q = 0; q < 4; ++q) {
            float v = ps[rt][q];
            v += __shfl_xor(v, 1, 64);
            v += __shfl_xor(v, 2, 64);
            v += __shfl_xor(v, 4, 64);
            v += __shfl_xor(v, 8, 64);
            if (r == 0)
                atomicAdd(&denom[rowbase + rt * 16 + g * 4 + q], v);
        }
}

// --- Kernel C: loss = (sum_i log denom_i - 20 * sum pos) / 2N ---
__global__ __launch_bounds__(1024) void finalize_kernel(
    const float* __restrict__ denom, const float* __restrict__ pos_part,
    float* __restrict__ out)
{
    int tid = threadIdx.x;
    float slog = 0.0f;
    #pragma unroll
    for (int u = 0; u < TN / 1024; ++u) slog += logf(denom[u * 1024 + tid]);
    float spos = pos_part[tid];
    #pragma unroll
    for (int m = 1; m < 64; m <<= 1) {
        slog += __shfl_xor(slog, m, 64);
        spos += __shfl_xor(spos, m, 64);
    }
    __shared__ float redl[16], redp[16];
    if ((tid & 63) == 0) { redl[tid >> 6] = slog; redp[tid >> 6] = spos; }
    __syncthreads();
    if (tid == 0) {
        float tl = 0.0f, tp = 0.0f;
        #pragma unroll
        for (int i = 0; i < 16; ++i) { tl += redl[i]; tp += redp[i]; }
        out[0] = (tl - 20.0f * tp) / (float)TN;
    }
}

extern "C" void kernel_launch(void* const* d_in, const int* in_sizes, int n_in,
                              void* d_out, int out_size, void* d_ws, size_t ws_size,
                              hipStream_t stream) {
    const float* anchor = (const float*)d_in[0];
    const float* target = (const float*)d_in[1];
    float* denom    = (float*)d_ws;
    float* pos_part = denom + TN;          // 1024 entries
    ushort* z       = (ushort*)((char*)d_ws + Z_BYTE_OFF);

    hipMemsetAsync(d_ws, 0, TN * sizeof(float), stream);
    prep_kernel<<<N_ROWS / 4, 256, 0, stream>>>(anchor, target, z, pos_part);
    simgemm_kernel<<<dim3(TN / 128, 16), 256, 0, stream>>>(z, denom);
    finalize_kernel<<<1, 1024, 0, stream>>>(denom, pos_part, (float*)d_out);
}